// Round 1
// baseline (626.026 us; speedup 1.0000x reference)
//
#include <hip/hip_runtime.h>
#include <stdint.h>

// Problem constants (fixed by the reference)
#define Yn 5
#define Nn 200000
#define Gn 128
#define In 128
#define Rn 3
#define Bn 1024
#define Kn 64
#define GIn (Gn * In)      // 16384
#define Mn (Yn * Bn)       // 5120 output rows
#define KKn (Rn * Gn)      // 384 GEMM K-dim

// ws layout (fp32):
//   [0, Mn*KKn*4)            A: means  [5120][384]   7,864,320 B
//   [+Mn*KKn*4, +3*GIn*4)    Weff [3][128][128]        196,608 B

// K0: Weff[0] = sum of 3 cite matrices; Weff[1,2] = W_rel[1,2].
__global__ __launch_bounds__(256) void k_weff(const float* __restrict__ Wrel,
                                              const float* __restrict__ Wcite,
                                              float* __restrict__ Weff) {
    int idx = blockIdx.x * 256 + threadIdx.x;           // [0, 16384)
    Weff[idx]            = Wcite[idx] + Wcite[GIn + idx] + Wcite[2 * GIn + idx];
    Weff[GIn + idx]      = Wrel[GIn + idx];
    Weff[2 * GIn + idx]  = Wrel[2 * GIn + idx];
}

// K1: 4 units per 256-thread block, one wave per (y,r,b) unit.
// CHANGES vs previous version:
//  (a) unit pinned to SGPR via readfirstlane -> neighbor indices come in via
//      s_load through the scalar cache (no ds_bpermute per row, address math
//      on SALU), removing one latency hop per 8-row batch.
//  (b) float4 loads, TWO rows per instruction: lanes 0-31 read the even
//      slot's row, lanes 32-63 the odd slot's row (16 B/lane, 1 KB per
//      global_load_dwordx4). Halves VMEM instruction count, doubles
//      in-flight bytes to 8 KB/wave/batch. Even/odd partials combined with
//      __shfl_xor(,32); lanes 0-31 write the float4 A row (same A layout).
// Tail: ONE masked 8-deep pair-batch (bounds wave-uniform; dead slots reload
// row nb[0] -> L1 hit) so the remainder costs 1 memory latency.
__global__ __launch_bounds__(256) void k_mean(const float4* __restrict__ emb4,
                                              const int* __restrict__ neighbors,
                                              const int* __restrict__ counts,
                                              float4* __restrict__ A4) {
    const int lane = threadIdx.x & 63;
    const int unit = __builtin_amdgcn_readfirstlane(blockIdx.x * 4 + (threadIdx.x >> 6));
    const int y = unit / (Rn * Bn);
    const int r = (unit >> 10) - y * Rn;
    const int b = unit & (Bn - 1);

    const int cnt = counts[unit];                       // s_load (uniform addr)
    const int* __restrict__ nb = neighbors + (size_t)unit * Kn;

    const int half = lane >> 5;                         // 0: even slots, 1: odd
    const int li   = lane & 31;                         // float4 column in row

    const float4* __restrict__ e = emb4 + (size_t)y * ((size_t)Nn * (Gn / 4));

    float ax = 0.f, ay = 0.f, az = 0.f, aw = 0.f;

    int k = 0;
    for (; k + 16 <= cnt; k += 16) {                    // 16 slots / iter
#pragma unroll
        for (int j = 0; j < 8; ++j) {                   // 8 loads, 2 rows each
            const int i0  = nb[k + 2 * j];              // s_load
            const int i1  = nb[k + 2 * j + 1];          // s_load
            const int idx = half ? i1 : i0;             // 1 v_cndmask
            const float4 u = e[(size_t)idx * (Gn / 4) + li];
            ax += u.x; ay += u.y; az += u.z; aw += u.w;
        }
    }
    if (k < cnt) {                                      // rem in 1..15, uniform
#pragma unroll
        for (int j = 0; j < 8; ++j) {
            const int s0  = k + 2 * j;
            const int i0  = nb[(s0 < cnt) ? s0 : 0];        // s_cselect + s_load
            const int i1  = nb[(s0 + 1 < cnt) ? (s0 + 1) : 0];
            const int idx = half ? i1 : i0;
            const int slot = s0 + half;
            const float4 u = e[(size_t)idx * (Gn / 4) + li]; // dead -> L1 hit
            const bool live = (slot < cnt);
            ax += live ? u.x : 0.f;
            ay += live ? u.y : 0.f;
            az += live ? u.z : 0.f;
            aw += live ? u.w : 0.f;
        }
    }

    // combine even-slot (lanes 0-31) and odd-slot (lanes 32-63) partials
    ax += __shfl_xor(ax, 32);
    ay += __shfl_xor(ay, 32);
    az += __shfl_xor(az, 32);
    aw += __shfl_xor(aw, 32);

    const float inv = 1.0f / (float)(cnt > 0 ? cnt : 1);
    if (half == 0) {
        // A[row = y*B + b][cols r*128 + 4*li .. +3]  (layout identical to before)
        A4[(size_t)(y * Bn + b) * (KKn / 4) + r * (Gn / 4) + li] =
            make_float4(ax * inv, ay * inv, az * inv, aw * inv);
    }
}

// K2: out[row][i] = sum_k A[row][k] * Weff[k][i].  Block = 8 rows x 128 cols
// (640 blocks -> ~2.5 waves/SIMD). A tile staged through LDS (12.3 KB,
// ds_read_b128 at wave-uniform addr = broadcast, conflict-free). W loads
// coalesced across i.  (UNCHANGED this round.)
#define ROWS_PER_BLK 8
__global__ __launch_bounds__(256) void k_out(const float* __restrict__ A,
                                             const float* __restrict__ W,
                                             float* __restrict__ out) {
    __shared__ float As[ROWS_PER_BLK * KKn];                // 8*384*4 = 12288 B
    const int t    = threadIdx.x;
    const int row0 = blockIdx.x * ROWS_PER_BLK;

    // stage A: 8*384 = 3072 floats = 768 float4, 256 threads -> 3 iters
    {
        const float4* src = (const float4*)(A + (size_t)row0 * KKn);
        float4* dst = (float4*)As;
#pragma unroll
        for (int j = 0; j < 3; ++j) dst[t + 256 * j] = src[t + 256 * j];
    }
    __syncthreads();

    const int i  = t & 127;
    const int rh = t >> 7;                                  // rows rh*4 .. rh*4+3
    float acc[4] = {0.f, 0.f, 0.f, 0.f};

#pragma unroll 2
    for (int q = 0; q < KKn / 4; ++q) {                     // 96 iters, 4 k each
        const float w0 = W[(4 * q + 0) * In + i];
        const float w1 = W[(4 * q + 1) * In + i];
        const float w2 = W[(4 * q + 2) * In + i];
        const float w3 = W[(4 * q + 3) * In + i];
#pragma unroll
        for (int j = 0; j < 4; ++j) {
            const float4 a = *(const float4*)(As + (rh * 4 + j) * KKn + 4 * q);
            acc[j] = fmaf(a.x, w0, fmaf(a.y, w1, fmaf(a.z, w2, fmaf(a.w, w3, acc[j]))));
        }
    }
#pragma unroll
    for (int j = 0; j < 4; ++j) {
        out[(size_t)(row0 + rh * 4 + j) * In + i] = acc[j];
    }
}

extern "C" void kernel_launch(void* const* d_in, const int* in_sizes, int n_in,
                              void* d_out, int out_size, void* d_ws, size_t ws_size,
                              hipStream_t stream) {
    const float* emb       = (const float*)d_in[0];   // fp32 [Y][N][G]
    const float* Wrel      = (const float*)d_in[1];   // fp32 [3][G][I]
    const float* Wcite     = (const float*)d_in[2];   // fp32 [3][G][I]
    const int*   neighbors = (const int*)d_in[3];     // int32 [Y][R][B][K]
    const int*   counts    = (const int*)d_in[4];     // int32 [Y][R][B]
    // d_in[5] = train_year (unused; Y fixed at 5)

    float* A    = (float*)d_ws;                                   // [5120][384]
    float* Weff = (float*)((char*)d_ws + (size_t)Mn * KKn * 4);   // [3][128][128]

    k_weff<<<GIn / 256, 256, 0, stream>>>(Wrel, Wcite, Weff);
    k_mean<<<(Yn * Rn * Bn) / 4, 256, 0, stream>>>((const float4*)emb, neighbors,
                                                   counts, (float4*)A);
    k_out<<<Mn / ROWS_PER_BLK, 256, 0, stream>>>(A, Weff, (float*)d_out);
}